// Round 21
// baseline (121.476 us; speedup 1.0000x reference)
//
#include <hip/hip_runtime.h>
#include <math.h>

#define NSAMP 32
#define XSTR  36                  // LDS row stride in floats (144B rows, 16B-aligned)
#define SQRT3 1.7320508075688772f

typedef _Float16 half8  __attribute__((ext_vector_type(8)));
typedef float    f32x16 __attribute__((ext_vector_type(16)));

// whole-wave broadcast from lane L (compile-time) — VALU op writing SGPR
__device__ __forceinline__ float rdlane(float v, int l) {
    return __int_as_float(__builtin_amdgcn_readlane(__float_as_int(v), l));
}

// ---- hybrid-transport packed 2-loc Cholesky ----
// pivot row element L[jj][K]: even chunks via LDS b128 broadcast (LDS pipe),
// odd chunks via dual compile-time readlane + select (VALU pipe).
// The two pipes carry ~half the 496-elem/lane transport volume each, concurrently.
template<int K, int C, bool ODD = ((C & 1) != 0)>
struct UpdH2;

template<int K, int C>
struct UpdH2<K, C, false> {            // even chunk: LDS broadcast
    static __device__ __forceinline__ void run(float* av, float lik, const float* pr, bool hi) {
        float4 pv = *reinterpret_cast<const float4*>(pr + 4 * C);   // b128, 2 addrs/wave
        if (4 * C + 0 > K) av[4 * C + 0] = fmaf(-lik, pv.x, av[4 * C + 0]);
        if (4 * C + 1 > K) av[4 * C + 1] = fmaf(-lik, pv.y, av[4 * C + 1]);
        if (4 * C + 2 > K) av[4 * C + 2] = fmaf(-lik, pv.z, av[4 * C + 2]);
        if (4 * C + 3 > K) av[4 * C + 3] = fmaf(-lik, pv.w, av[4 * C + 3]);
        UpdH2<K, C + 1>::run(av, lik, pr, hi);
    }
};

template<int K, int C>
struct UpdH2<K, C, true> {             // odd chunk: dual-readlane (VALU pipe)
    static __device__ __forceinline__ void run(float* av, float lik, const float* pr, bool hi) {
#pragma unroll
        for (int e = 0; e < 4; ++e) {
            if (4 * C + e > K) {
                float pa = rdlane(lik, 4 * C + e);        // loc A pivot elem
                float pb = rdlane(lik, 4 * C + e + 32);   // loc B pivot elem
                av[4 * C + e] = fmaf(-lik, hi ? pb : pa, av[4 * C + e]);
            }
        }
        UpdH2<K, C + 1>::run(av, lik, pr, hi);
    }
};

template<int K>
struct UpdH2<K, 8, false> {
    static __device__ __forceinline__ void run(float*, float, const float*, bool) {}
};

template<int K>
struct CholH2 {
    static __device__ __forceinline__ void run(float* av, float* pw, const float* pr, bool hi) {
        float dA = rdlane(av[K], K);          // loc A diag (lane K)
        float dB = rdlane(av[K], K + 32);     // loc B diag (lane K+32)
        float lik = av[K] * __frsqrt_rn(hi ? dB : dA);   // L[i][k], i>=k
        av[K] = lik;
        *pw = lik;                            // ds_write_b32 into own half's slot
        UpdH2<K, (K + 1) / 4>::run(av, lik, pr, hi);
        CholH2<K + 1>::run(av, pw, pr, hi);
    }
};
template<>
struct CholH2<NSAMP> {
    static __device__ __forceinline__ void run(float*, float*, const float*, bool) {}
};

// ================= K1: build g (MFMA gram + matern epilogue) — R10-verified =================
__global__ __launch_bounds__(256, 6) void g_kernel(
    const float* __restrict__ aug,     // (32, n_loc, 31)
    const float* __restrict__ scales,  // (n_loc)
    const float* __restrict__ nug,     // (n_loc)
    const float* __restrict__ frac,    // (1)
    const int*   __restrict__ bidx,    // (n_loc)
    const float* __restrict__ thq,     // (1)
    const float* __restrict__ sigp,    // (2)
    const float* __restrict__ lens,    // (1)
    float* __restrict__ out,
    int n_loc)
{
    // all LDS is wave-private -> no __syncthreads anywhere
    __shared__ __align__(16) float X[4][NSAMP][XSTR];
    __shared__ float SQ[4][NSAMP];

    const int tid  = threadIdx.x;
    const int w    = tid >> 6;        // wave index = which location of this block
    const int lane = tid & 63;
    const int j    = lane & 31;       // Gram column owned by this lane
    const int hl   = lane >> 5;       // k-slice half
    const int kb   = 8 * hl;

    const int loc0 = blockIdx.x * 4;
    int loc = loc0 + w; if (loc >= n_loc) loc = n_loc - 1;

    const size_t srow = (size_t)n_loc * 31;

    // ---- uniform scalars + per-lane feature scales ----
    const float a_s   = -0.5f * __expf(thq[0]);
    const float invls = 1.0f / (__expf(lens[0]) * SQRT3);
    float sl[8], sh[8];
#pragma unroll
    for (int e = 0; e < 8; ++e) {
        sl[e] = __expf(a_s * (float)(kb + e + 1))  * invls;   // k = kb+e
        sh[e] = __expf(a_s * (float)(kb + e + 17)) * invls;   // k = 16+kb+e
    }

    // ---- stage this wave's location coalesced into X[w] (NaN-fixed) ----
    if (lane < 60) {
        const int s0 = lane / 30;           // 0,1
        const int k  = lane - s0 * 30;      // 0..29
        const float* p = aug + (size_t)s0 * srow + (size_t)loc * 31 + 1 + k;
        float* xp = &X[w][s0][k];
#pragma unroll
        for (int it = 0; it < 16; ++it) {   // s = 2*it + s0 covers 0..31
            float v = p[(size_t)(2 * it) * srow];
            v = (v != v) ? 0.0f : v;        // isnan -> 0
            xp[2 * it * XSTR] = v;
        }
    }
    // zero-pad k=30,31 for all 32 rows
    X[w][lane >> 1][30 + (lane & 1)] = 0.0f;

    // ---- frag load (row j, own k-slice) + scale + f16 convert + norm ----
    const float* xr = &X[w][j][0];
    float4 r0 = *reinterpret_cast<const float4*>(xr + kb);
    float4 r1 = *reinterpret_cast<const float4*>(xr + kb + 4);
    float4 r2 = *reinterpret_cast<const float4*>(xr + 16 + kb);
    float4 r3 = *reinterpret_cast<const float4*>(xr + 16 + kb + 4);
    float v0[8] = {r0.x, r0.y, r0.z, r0.w, r1.x, r1.y, r1.z, r1.w};
    float v1[8] = {r2.x, r2.y, r2.z, r2.w, r3.x, r3.y, r3.z, r3.w};

    half8 fLo, fHi;
    float s0a = 0.f, s1a = 0.f;
#pragma unroll
    for (int e = 0; e < 8; ++e) {
        float a = v0[e] * sl[e];
        s0a = fmaf(a, a, s0a);
        fLo[e] = (_Float16)a;
        float b = v1[e] * sh[e];
        s1a = fmaf(b, b, s1a);
        fHi[e] = (_Float16)b;
    }
    float sqp    = s0a + s1a;
    float sqfull = sqp + __shfl_xor(sqp, 32);   // |x_row_j|^2
    if (hl == 0) SQ[w][j] = sqfull;             // same-wave LDS: in-order, no barrier

    // ---- Gram: G = Xl * Xl^T (A-frag == B-frag) ----
    f32x16 C = {};
    C = __builtin_amdgcn_mfma_f32_32x32x16_f16(fLo, fLo, C, 0, 0, 0);
    C = __builtin_amdgcn_mfma_f32_32x32x16_f16(fHi, fHi, C, 0, 0, 0);

    // ---- per-location coefficient ----
    const float scl = scales[loc];
    const float nm  = nug[loc];
    const float sig  = __expf(sigp[0] + sigp[1] * __logf(scl));
    const float coef = frac[0] * sig * sig / nm;
    const bool  bz   = (bidx[loc] == 0);

    // ---- matern epilogue on C (col=j, row=(r&3)+8*(r>>2)+4*hl); store g ----
    float* gout = out + (size_t)loc * 1024;
    const float* sqb = &SQ[w][4 * hl];
#pragma unroll
    for (int r = 0; r < 16; ++r) {
        const int row0 = (r & 3) + 8 * (r >> 2);
        const int i    = row0 + 4 * hl;
        const bool dia = (j == i);
        float sqi = sqb[row0];                         // ds_read b32 (broadcast per half)
        float d2  = fmaf(-2.0f, C[r], sqi + sqfull);
        d2 = dia ? 0.0f : fmaxf(d2, 0.0f);
        float s3d = __fsqrt_rn(3.0f * d2);
        float nl  = (1.0f + s3d) * __expf(-s3d);
        float dg  = dia ? 1.0f : 0.0f;
        float gv  = fmaf(coef, nl, dg);
        if (bz) gv = dg;
        gout[i * 32 + j] = gv;                         // 2x128B lines per instr
    }

    // ---- nug_mean passthrough ----
    if (tid < 4) {
        int lc = loc0 + tid; if (lc >= n_loc) lc = n_loc - 1;
        out[(size_t)n_loc * 2048 + lc] = nug[lc];
    }
}

// ================= K2: packed Cholesky — 2 loc/wave, hybrid LDS+VALU transport =================
__global__ __launch_bounds__(256, 6) void chol_kernel(   // proven no-spill budget (cap 85)
    const float* __restrict__ g,       // (n_loc, 32, 32) — K1's output, L2/L3-resident
    float* __restrict__ lout,          // (n_loc, 32, 32)
    int n_loc)
{
    __shared__ __align__(16) float P[4][64];   // per-wave pivot rows: [0..31]=locA, [32..63]=locB

    const int tid  = threadIdx.x;
    const int w    = tid >> 6;
    const int lane = tid & 63;
    const int j    = lane & 31;
    const int hl   = lane >> 5;       // which of this wave's 2 locations

    const int locA = blockIdx.x * 8 + w * 2;   // 30000 % 8 == 0: clamp never fires
    int locB = locA + 1; if (locB >= n_loc) locB = n_loc - 1;
    const int loc  = hl ? locB : locA;

    // every lane loads a unique row: lanes 0-31 -> locA rows, 32-63 -> locB rows
    const float* grow = g + (size_t)loc * 1024 + (size_t)j * 32;
    float av[32];
#pragma unroll
    for (int c = 0; c < 8; ++c) {
        float4 v = *reinterpret_cast<const float4*>(grow + 4 * c);
        av[4 * c + 0] = v.x; av[4 * c + 1] = v.y;
        av[4 * c + 2] = v.z; av[4 * c + 3] = v.w;
    }

    // one 32-step chain factors both matrices; transport split across LDS + VALU pipes
    CholH2<0>::run(av, &P[w][lane], &P[w][hl * 32], hl != 0);

    // all 64 lanes store their own location's masked row
    float* lrow = lout + (size_t)loc * 1024 + (size_t)j * 32;
#pragma unroll
    for (int c = 0; c < 8; ++c) {
        float4 wv;
        wv.x = (4 * c + 0 <= j) ? av[4 * c + 0] : 0.f;
        wv.y = (4 * c + 1 <= j) ? av[4 * c + 1] : 0.f;
        wv.z = (4 * c + 2 <= j) ? av[4 * c + 2] : 0.f;
        wv.w = (4 * c + 3 <= j) ? av[4 * c + 3] : 0.f;
        *reinterpret_cast<float4*>(&lrow[4 * c]) = wv;
    }
}

extern "C" void kernel_launch(void* const* d_in, const int* in_sizes, int n_in,
                              void* d_out, int out_size, void* d_ws, size_t ws_size,
                              hipStream_t stream) {
    const float* aug    = (const float*)d_in[0];
    const float* scales = (const float*)d_in[1];
    const float* nug    = (const float*)d_in[2];
    const float* frac   = (const float*)d_in[3];
    const int*   bidx   = (const int*)  d_in[4];
    const float* thq    = (const float*)d_in[5];
    const float* sigp   = (const float*)d_in[6];
    const float* lens   = (const float*)d_in[7];
    const int n_loc = in_sizes[1];

    float* out = (float*)d_out;

    g_kernel<<<(n_loc + 3) / 4, 256, 0, stream>>>(aug, scales, nug, frac, bidx, thq,
                                                  sigp, lens, out, n_loc);
    chol_kernel<<<(n_loc + 7) / 8, 256, 0, stream>>>(out, out + (size_t)n_loc * 1024, n_loc);
}

// Round 22
// 109.748 us; speedup vs baseline: 1.1069x; 1.1069x over previous
//
#include <hip/hip_runtime.h>
#include <math.h>

#define NSAMP 32
#define XSTR  36                  // LDS row stride in floats (144B rows, 16B-aligned)
#define SQRT3 1.7320508075688772f

typedef _Float16 half8  __attribute__((ext_vector_type(8)));
typedef float    f32x16 __attribute__((ext_vector_type(16)));

// whole-wave broadcast from lane L (compile-time) — VALU op writing SGPR
__device__ __forceinline__ float rdlane(float v, int l) {
    return __int_as_float(__builtin_amdgcn_readlane(__float_as_int(v), l));
}

// ---- packed 2-loc LDS-pivot-row Cholesky (R18-verified best) ----
// lanes 0-31: loc A rows, pivots in P[0..31]; lanes 32-63: loc B rows, pivots in P[32..63]
// diag: dual compile-time readlane + cndmask (only lane-crossing op; 3 instr/step)
template<int K, int C>
struct UpdC2 {
    static __device__ __forceinline__ void run(float* av, float lik, const float* pr) {
        float4 pv = *reinterpret_cast<const float4*>(pr + 4 * C);   // b128, 2 addrs/wave
        if (4 * C + 0 > K) av[4 * C + 0] = fmaf(-lik, pv.x, av[4 * C + 0]);
        if (4 * C + 1 > K) av[4 * C + 1] = fmaf(-lik, pv.y, av[4 * C + 1]);
        if (4 * C + 2 > K) av[4 * C + 2] = fmaf(-lik, pv.z, av[4 * C + 2]);
        if (4 * C + 3 > K) av[4 * C + 3] = fmaf(-lik, pv.w, av[4 * C + 3]);
        UpdC2<K, C + 1>::run(av, lik, pr);
    }
};
template<int K>
struct UpdC2<K, 8> { static __device__ __forceinline__ void run(float*, float, const float*) {} };

template<int K>
struct CholP2 {
    static __device__ __forceinline__ void run(float* av, float* pw, const float* pr, bool hi) {
        float dA = rdlane(av[K], K);          // loc A diag (lane K)
        float dB = rdlane(av[K], K + 32);     // loc B diag (lane K+32)
        float lik = av[K] * __frsqrt_rn(hi ? dB : dA);   // L[i][k], i>=k
        av[K] = lik;
        *pw = lik;                            // ds_write_b32 into own half's slot
        UpdC2<K, (K + 1) / 4>::run(av, lik, pr);
        CholP2<K + 1>::run(av, pw, pr, hi);
    }
};
template<>
struct CholP2<NSAMP> {
    static __device__ __forceinline__ void run(float*, float*, const float*, bool) {}
};

// ================= K1: build g (MFMA gram + matern epilogue) — R10-verified =================
__global__ __launch_bounds__(256, 6) void g_kernel(
    const float* __restrict__ aug,     // (32, n_loc, 31)
    const float* __restrict__ scales,  // (n_loc)
    const float* __restrict__ nug,     // (n_loc)
    const float* __restrict__ frac,    // (1)
    const int*   __restrict__ bidx,    // (n_loc)
    const float* __restrict__ thq,     // (1)
    const float* __restrict__ sigp,    // (2)
    const float* __restrict__ lens,    // (1)
    float* __restrict__ out,
    int n_loc)
{
    // all LDS is wave-private -> no __syncthreads anywhere
    __shared__ __align__(16) float X[4][NSAMP][XSTR];
    __shared__ float SQ[4][NSAMP];

    const int tid  = threadIdx.x;
    const int w    = tid >> 6;        // wave index = which location of this block
    const int lane = tid & 63;
    const int j    = lane & 31;       // Gram column owned by this lane
    const int hl   = lane >> 5;       // k-slice half
    const int kb   = 8 * hl;

    const int loc0 = blockIdx.x * 4;
    int loc = loc0 + w; if (loc >= n_loc) loc = n_loc - 1;

    const size_t srow = (size_t)n_loc * 31;

    // ---- uniform scalars + per-lane feature scales ----
    const float a_s   = -0.5f * __expf(thq[0]);
    const float invls = 1.0f / (__expf(lens[0]) * SQRT3);
    float sl[8], sh[8];
#pragma unroll
    for (int e = 0; e < 8; ++e) {
        sl[e] = __expf(a_s * (float)(kb + e + 1))  * invls;   // k = kb+e
        sh[e] = __expf(a_s * (float)(kb + e + 17)) * invls;   // k = 16+kb+e
    }

    // ---- stage this wave's location coalesced into X[w] (NaN-fixed) ----
    if (lane < 60) {
        const int s0 = lane / 30;           // 0,1
        const int k  = lane - s0 * 30;      // 0..29
        const float* p = aug + (size_t)s0 * srow + (size_t)loc * 31 + 1 + k;
        float* xp = &X[w][s0][k];
#pragma unroll
        for (int it = 0; it < 16; ++it) {   // s = 2*it + s0 covers 0..31
            float v = p[(size_t)(2 * it) * srow];
            v = (v != v) ? 0.0f : v;        // isnan -> 0
            xp[2 * it * XSTR] = v;
        }
    }
    // zero-pad k=30,31 for all 32 rows
    X[w][lane >> 1][30 + (lane & 1)] = 0.0f;

    // ---- frag load (row j, own k-slice) + scale + f16 convert + norm ----
    const float* xr = &X[w][j][0];
    float4 r0 = *reinterpret_cast<const float4*>(xr + kb);
    float4 r1 = *reinterpret_cast<const float4*>(xr + kb + 4);
    float4 r2 = *reinterpret_cast<const float4*>(xr + 16 + kb);
    float4 r3 = *reinterpret_cast<const float4*>(xr + 16 + kb + 4);
    float v0[8] = {r0.x, r0.y, r0.z, r0.w, r1.x, r1.y, r1.z, r1.w};
    float v1[8] = {r2.x, r2.y, r2.z, r2.w, r3.x, r3.y, r3.z, r3.w};

    half8 fLo, fHi;
    float s0a = 0.f, s1a = 0.f;
#pragma unroll
    for (int e = 0; e < 8; ++e) {
        float a = v0[e] * sl[e];
        s0a = fmaf(a, a, s0a);
        fLo[e] = (_Float16)a;
        float b = v1[e] * sh[e];
        s1a = fmaf(b, b, s1a);
        fHi[e] = (_Float16)b;
    }
    float sqp    = s0a + s1a;
    float sqfull = sqp + __shfl_xor(sqp, 32);   // |x_row_j|^2
    if (hl == 0) SQ[w][j] = sqfull;             // same-wave LDS: in-order, no barrier

    // ---- Gram: G = Xl * Xl^T (A-frag == B-frag) ----
    f32x16 C = {};
    C = __builtin_amdgcn_mfma_f32_32x32x16_f16(fLo, fLo, C, 0, 0, 0);
    C = __builtin_amdgcn_mfma_f32_32x32x16_f16(fHi, fHi, C, 0, 0, 0);

    // ---- per-location coefficient ----
    const float scl = scales[loc];
    const float nm  = nug[loc];
    const float sig  = __expf(sigp[0] + sigp[1] * __logf(scl));
    const float coef = frac[0] * sig * sig / nm;
    const bool  bz   = (bidx[loc] == 0);

    // ---- matern epilogue on C (col=j, row=(r&3)+8*(r>>2)+4*hl); store g ----
    float* gout = out + (size_t)loc * 1024;
    const float* sqb = &SQ[w][4 * hl];
#pragma unroll
    for (int r = 0; r < 16; ++r) {
        const int row0 = (r & 3) + 8 * (r >> 2);
        const int i    = row0 + 4 * hl;
        const bool dia = (j == i);
        float sqi = sqb[row0];                         // ds_read b32 (broadcast per half)
        float d2  = fmaf(-2.0f, C[r], sqi + sqfull);
        d2 = dia ? 0.0f : fmaxf(d2, 0.0f);
        float s3d = __fsqrt_rn(3.0f * d2);
        float nl  = (1.0f + s3d) * __expf(-s3d);
        float dg  = dia ? 1.0f : 0.0f;
        float gv  = fmaf(coef, nl, dg);
        if (bz) gv = dg;
        gout[i * 32 + j] = gv;                         // 2x128B lines per instr
    }

    // ---- nug_mean passthrough ----
    if (tid < 4) {
        int lc = loc0 + tid; if (lc >= n_loc) lc = n_loc - 1;
        out[(size_t)n_loc * 2048 + lc] = nug[lc];
    }
}

// ================= K2: packed Cholesky — 2 locations per wave, LDS pivot fabric =================
__global__ __launch_bounds__(256, 6) void chol_kernel(   // proven no-spill budget (cap 85)
    const float* __restrict__ g,       // (n_loc, 32, 32) — K1's output, L2/L3-resident
    float* __restrict__ lout,          // (n_loc, 32, 32)
    int n_loc)
{
    __shared__ __align__(16) float P[4][64];   // per-wave pivot rows: [0..31]=locA, [32..63]=locB

    const int tid  = threadIdx.x;
    const int w    = tid >> 6;
    const int lane = tid & 63;
    const int j    = lane & 31;
    const int hl   = lane >> 5;       // which of this wave's 2 locations

    const int locA = blockIdx.x * 8 + w * 2;   // 30000 % 8 == 0: clamp never fires
    int locB = locA + 1; if (locB >= n_loc) locB = n_loc - 1;
    const int loc  = hl ? locB : locA;

    // every lane loads a unique row: lanes 0-31 -> locA rows, 32-63 -> locB rows
    const float* grow = g + (size_t)loc * 1024 + (size_t)j * 32;
    float av[32];
#pragma unroll
    for (int c = 0; c < 8; ++c) {
        float4 v = *reinterpret_cast<const float4*>(grow + 4 * c);
        av[4 * c + 0] = v.x; av[4 * c + 1] = v.y;
        av[4 * c + 2] = v.z; av[4 * c + 3] = v.w;
    }

    // one 32-step chain factors both matrices
    CholP2<0>::run(av, &P[w][lane], &P[w][hl * 32], hl != 0);

    // all 64 lanes store their own location's masked row
    float* lrow = lout + (size_t)loc * 1024 + (size_t)j * 32;
#pragma unroll
    for (int c = 0; c < 8; ++c) {
        float4 wv;
        wv.x = (4 * c + 0 <= j) ? av[4 * c + 0] : 0.f;
        wv.y = (4 * c + 1 <= j) ? av[4 * c + 1] : 0.f;
        wv.z = (4 * c + 2 <= j) ? av[4 * c + 2] : 0.f;
        wv.w = (4 * c + 3 <= j) ? av[4 * c + 3] : 0.f;
        *reinterpret_cast<float4*>(&lrow[4 * c]) = wv;
    }
}

extern "C" void kernel_launch(void* const* d_in, const int* in_sizes, int n_in,
                              void* d_out, int out_size, void* d_ws, size_t ws_size,
                              hipStream_t stream) {
    const float* aug    = (const float*)d_in[0];
    const float* scales = (const float*)d_in[1];
    const float* nug    = (const float*)d_in[2];
    const float* frac   = (const float*)d_in[3];
    const int*   bidx   = (const int*)  d_in[4];
    const float* thq    = (const float*)d_in[5];
    const float* sigp   = (const float*)d_in[6];
    const float* lens   = (const float*)d_in[7];
    const int n_loc = in_sizes[1];

    float* out = (float*)d_out;

    g_kernel<<<(n_loc + 3) / 4, 256, 0, stream>>>(aug, scales, nug, frac, bidx, thq,
                                                  sigp, lens, out, n_loc);
    chol_kernel<<<(n_loc + 7) / 8, 256, 0, stream>>>(out, out + (size_t)n_loc * 1024, n_loc);
}